// Round 3
// baseline (58.081 us; speedup 1.0000x reference)
//
#include <hip/hip_runtime.h>
#include <hip/hip_bf16.h>

#define B_SZ 256
#define N_SZ 2000
#define N_PAD 2048
#define D_SZ 512
#define C_SZ 100
#define BT 4          // batch rows per thread
#define D4 (D_SZ / 4) // 128 float4 chunks per row

// ---------------------------------------------------------------------------
// Prep: label one-hot -> class index per support sample + class counts
// ---------------------------------------------------------------------------
__global__ void prep_kernel(const float* __restrict__ labels,
                            int* __restrict__ idx,
                            float* __restrict__ counts) {
    int n = blockIdx.x * 256 + threadIdx.x;
    if (n < N_SZ) {
        const float* row = labels + (size_t)n * C_SZ;
        int c = 0;
        for (int j = 0; j < C_SZ; ++j) {
            if (row[j] > 0.5f) c = j;
        }
        idx[n] = c;
        atomicAdd(&counts[c], 1.0f);
    }
}

// ---------------------------------------------------------------------------
// Transpose support [N][D4] float4 -> [D4][N_PAD] float4 so the score
// kernel's per-lane stream is coalesced (lanes consecutive in n).
// Writes are coalesced (tid contiguous in n); one-time 8 MB traffic.
// ---------------------------------------------------------------------------
__global__ void transpose_kernel(const float4* __restrict__ sup4,
                                 float4* __restrict__ supT4) {
    int t = blockIdx.x * 256 + threadIdx.x; // t = dc * N_PAD + n
    int dc = t >> 11;                       // / N_PAD
    int n  = t & (N_PAD - 1);
    float4 v = make_float4(0.f, 0.f, 0.f, 0.f);
    if (n < N_SZ) v = sup4[(size_t)n * D4 + dc];
    supT4[t] = v;
}

// ---------------------------------------------------------------------------
// Main: each thread owns one support sample n and BT batch rows.
// supT4[dc][n]: lanes read consecutive float4 -> 1 coalesced 1KB wave load.
// inputs/w indexed only by uniform (b, dc) -> scalar (SGPR) loads.
// inner op: acc += w_d * |a_bd - s_nd|  ==  v_sub(s,v) + v_fma(s, abs(v), acc)
// ---------------------------------------------------------------------------
__global__ __launch_bounds__(256, 2) void score_kernel(
    const float4* __restrict__ inp4,   // [B][D4]
    const float4* __restrict__ supT4,  // [D4][N_PAD]
    const float4* __restrict__ w4,     // [D4]
    const float* __restrict__ bias_p,  // [1]
    const int* __restrict__ idx,       // [N]
    float* __restrict__ out)           // [B][C] (atomically accumulated)
{
    int n = blockIdx.x * 256 + threadIdx.x;
    int b0 = blockIdx.y * BT;
    bool active = (n < N_SZ);

    float acc[BT];
#pragma unroll
    for (int i = 0; i < BT; ++i) acc[i] = 0.0f;

#pragma unroll 8
    for (int dc = 0; dc < D4; ++dc) {
        float4 sv = supT4[(size_t)dc * N_PAD + n];
        float4 wv = w4[dc];
#pragma unroll
        for (int i = 0; i < BT; ++i) {
            float4 av = inp4[(size_t)(b0 + i) * D4 + dc];
            acc[i] += wv.x * fabsf(av.x - sv.x);
            acc[i] += wv.y * fabsf(av.y - sv.y);
            acc[i] += wv.z * fabsf(av.z - sv.z);
            acc[i] += wv.w * fabsf(av.w - sv.w);
        }
    }

    if (active) {
        float bias = *bias_p;
        int c = idx[n];
#pragma unroll
        for (int i = 0; i < BT; ++i) {
            float s = 1.0f / (1.0f + __expf(-(acc[i] + bias)));
            atomicAdd(&out[(size_t)(b0 + i) * C_SZ + c], s);
        }
    }
}

// ---------------------------------------------------------------------------
// Epilogue: divide class sums by class counts (divide_no_nan semantics)
// ---------------------------------------------------------------------------
__global__ void div_kernel(float* __restrict__ out,
                           const float* __restrict__ counts) {
    int i = blockIdx.x * 256 + threadIdx.x;
    if (i < B_SZ * C_SZ) {
        float cnt = counts[i % C_SZ];
        float v = out[i];
        out[i] = (cnt != 0.0f) ? v / cnt : 0.0f;
    }
}

extern "C" void kernel_launch(void* const* d_in, const int* in_sizes, int n_in,
                              void* d_out, int out_size, void* d_ws, size_t ws_size,
                              hipStream_t stream) {
    const float* inputs  = (const float*)d_in[0]; // [B, D]
    const float* support = (const float*)d_in[1]; // [N, D]
    const float* labels  = (const float*)d_in[2]; // [N, C]
    const float* w       = (const float*)d_in[3]; // [D]
    const float* bias    = (const float*)d_in[4]; // [1]
    float* out = (float*)d_out;                   // [B, C]

    // Workspace layout: idx[2048] ints (8KB), counts[128] floats, pad to 16KB,
    // then supT4 [D4][N_PAD] float4 = 4MB.
    int*    idx    = (int*)d_ws;
    float*  counts = (float*)((char*)d_ws + 2048 * sizeof(int));
    float4* supT4  = (float4*)((char*)d_ws + 16384);

    // Zero accumulation targets (harness poisons them to 0xAA)
    hipMemsetAsync(out, 0, (size_t)out_size * sizeof(float), stream);
    hipMemsetAsync(d_ws, 0, 16384, stream);

    prep_kernel<<<dim3((N_SZ + 255) / 256), dim3(256), 0, stream>>>(labels, idx, counts);

    transpose_kernel<<<dim3(D4 * N_PAD / 256), dim3(256), 0, stream>>>(
        (const float4*)support, supT4);

    dim3 grid(N_PAD / 256, B_SZ / BT); // 8 x 64 = 512 blocks, 2 waves/SIMD
    score_kernel<<<grid, dim3(256), 0, stream>>>(
        (const float4*)inputs, supT4, (const float4*)w,
        bias, idx, out);

    div_kernel<<<dim3((B_SZ * C_SZ + 255) / 256), dim3(256), 0, stream>>>(out, counts);
}

// Round 4
// 54.745 us; speedup vs baseline: 1.0609x; 1.0609x over previous
//
#include <hip/hip_runtime.h>
#include <hip/hip_bf16.h>

#define B_SZ 256
#define N_SZ 2000
#define N_PAD 2048
#define D_SZ 512
#define C_SZ 100
#define BT 4          // batch rows per thread
#define D4 (D_SZ / 4) // 128 float4 chunks per row
#define PF 4          // prefetch depth (dc groups of 4)

// ---------------------------------------------------------------------------
// Prep: label one-hot -> class index per support sample + class counts
// ---------------------------------------------------------------------------
__global__ void prep_kernel(const float* __restrict__ labels,
                            int* __restrict__ idx,
                            float* __restrict__ counts) {
    int n = blockIdx.x * 256 + threadIdx.x;
    if (n < N_SZ) {
        const float* row = labels + (size_t)n * C_SZ;
        int c = 0;
        for (int j = 0; j < C_SZ; ++j) {
            if (row[j] > 0.5f) c = j;
        }
        idx[n] = c;
        atomicAdd(&counts[c], 1.0f);
    }
}

// ---------------------------------------------------------------------------
// Transpose support [N][D4] float4 -> [D4][N_PAD] float4 (coalesced stream)
// ---------------------------------------------------------------------------
__global__ void transpose_kernel(const float4* __restrict__ sup4,
                                 float4* __restrict__ supT4) {
    int t = blockIdx.x * 256 + threadIdx.x; // t = dc * N_PAD + n
    int dc = t >> 11;                       // / N_PAD
    int n  = t & (N_PAD - 1);
    float4 v = make_float4(0.f, 0.f, 0.f, 0.f);
    if (n < N_SZ) v = sup4[(size_t)n * D4 + dc];
    supT4[t] = v;
}

// ---------------------------------------------------------------------------
// Main. Round-3 failure: VGPR=16 -> compiler serialized all loads.
// Fix: inputs/w staged in LDS (broadcast ds_read, kills s_load SGPR pressure);
// support stream manually double-buffered in named registers so 4 coalesced
// VMEM loads stay in flight under 256 SIMD-cycles of VALU.
// ---------------------------------------------------------------------------
__global__ __launch_bounds__(256, 2) void score_kernel(
    const float4* __restrict__ inp4,   // [B][D4]
    const float4* __restrict__ supT4,  // [D4][N_PAD]
    const float4* __restrict__ w4,     // [D4]
    const float* __restrict__ bias_p,  // [1]
    const int* __restrict__ idx,       // [N]
    float* __restrict__ out)           // [B][C] (atomically accumulated)
{
    __shared__ float4 inp_s[BT][D4]; // 8 KB
    __shared__ float4 w_s[D4];       // 2 KB

    int tid = threadIdx.x;
    int n  = blockIdx.x * 256 + tid;
    int b0 = blockIdx.y * BT;

    // Cooperative stage: BT input rows + w into LDS (one-time, coalesced)
#pragma unroll
    for (int t = tid; t < BT * D4; t += 256)
        inp_s[t >> 7][t & 127] = inp4[(size_t)(b0 + (t >> 7)) * D4 + (t & 127)];
    if (tid < D4) w_s[tid] = w4[tid];
    __syncthreads();

    const float4* __restrict__ sp = supT4 + n;

    float acc[BT] = {0.f, 0.f, 0.f, 0.f};

    auto compute = [&](int dc, const float4& sv) {
        float4 wv = w_s[dc];
#pragma unroll
        for (int i = 0; i < BT; ++i) {
            float4 av = inp_s[i][dc];
            acc[i] += wv.x * fabsf(av.x - sv.x);
            acc[i] += wv.y * fabsf(av.y - sv.y);
            acc[i] += wv.z * fabsf(av.z - sv.z);
            acc[i] += wv.w * fabsf(av.w - sv.w);
        }
    };

    // Manual software pipeline: prefetch next PF support chunks into named
    // registers while computing the current PF chunks.
    float4 c0 = sp[(size_t)0 * N_PAD];
    float4 c1 = sp[(size_t)1 * N_PAD];
    float4 c2 = sp[(size_t)2 * N_PAD];
    float4 c3 = sp[(size_t)3 * N_PAD];

#pragma unroll 1
    for (int dc = 0; dc < D4 - PF; dc += PF) {
        float4 t0 = sp[(size_t)(dc + 4) * N_PAD];
        float4 t1 = sp[(size_t)(dc + 5) * N_PAD];
        float4 t2 = sp[(size_t)(dc + 6) * N_PAD];
        float4 t3 = sp[(size_t)(dc + 7) * N_PAD];
        compute(dc + 0, c0);
        compute(dc + 1, c1);
        compute(dc + 2, c2);
        compute(dc + 3, c3);
        c0 = t0; c1 = t1; c2 = t2; c3 = t3;
    }
    compute(D4 - 4, c0);
    compute(D4 - 3, c1);
    compute(D4 - 2, c2);
    compute(D4 - 1, c3);

    if (n < N_SZ) {
        float bias = *bias_p;
        int c = idx[n];
#pragma unroll
        for (int i = 0; i < BT; ++i) {
            float s = 1.0f / (1.0f + __expf(-(acc[i] + bias)));
            atomicAdd(&out[(size_t)(b0 + i) * C_SZ + c], s);
        }
    }
}

// ---------------------------------------------------------------------------
// Epilogue: divide class sums by class counts (divide_no_nan semantics)
// ---------------------------------------------------------------------------
__global__ void div_kernel(float* __restrict__ out,
                           const float* __restrict__ counts) {
    int i = blockIdx.x * 256 + threadIdx.x;
    if (i < B_SZ * C_SZ) {
        float cnt = counts[i % C_SZ];
        float v = out[i];
        out[i] = (cnt != 0.0f) ? v / cnt : 0.0f;
    }
}

extern "C" void kernel_launch(void* const* d_in, const int* in_sizes, int n_in,
                              void* d_out, int out_size, void* d_ws, size_t ws_size,
                              hipStream_t stream) {
    const float* inputs  = (const float*)d_in[0]; // [B, D]
    const float* support = (const float*)d_in[1]; // [N, D]
    const float* labels  = (const float*)d_in[2]; // [N, C]
    const float* w       = (const float*)d_in[3]; // [D]
    const float* bias    = (const float*)d_in[4]; // [1]
    float* out = (float*)d_out;                   // [B, C]

    // Workspace layout: idx[2048] ints (8KB), counts[128] floats, pad to 16KB,
    // then supT4 [D4][N_PAD] float4 = 4MB.
    int*    idx    = (int*)d_ws;
    float*  counts = (float*)((char*)d_ws + 2048 * sizeof(int));
    float4* supT4  = (float4*)((char*)d_ws + 16384);

    // Zero accumulation targets (harness poisons them to 0xAA)
    hipMemsetAsync(out, 0, (size_t)out_size * sizeof(float), stream);
    hipMemsetAsync(d_ws, 0, 16384, stream);

    prep_kernel<<<dim3((N_SZ + 255) / 256), dim3(256), 0, stream>>>(labels, idx, counts);

    transpose_kernel<<<dim3(D4 * N_PAD / 256), dim3(256), 0, stream>>>(
        (const float4*)support, supT4);

    dim3 grid(N_PAD / 256, B_SZ / BT); // 8 x 64 = 512 blocks, 2 waves/SIMD
    score_kernel<<<grid, dim3(256), 0, stream>>>(
        (const float4*)inputs, supT4, (const float4*)w,
        bias, idx, out);

    div_kernel<<<dim3((B_SZ * C_SZ + 255) / 256), dim3(256), 0, stream>>>(out, counts);
}

// Round 5
// 45.552 us; speedup vs baseline: 1.2750x; 1.2018x over previous
//
#include <hip/hip_runtime.h>
#include <hip/hip_bf16.h>

#define B_SZ 256
#define N_SZ 2000
#define N_PAD 2048
#define D_SZ 512
#define C_SZ 100
#define BT 4          // batch rows per thread
#define D4 (D_SZ / 4) // 128 float4 chunks per row
#define PF 4          // support prefetch depth (dc steps)

// ---------------------------------------------------------------------------
// Prep: one-hot labels -> class index per support sample (no atomics)
// ---------------------------------------------------------------------------
__global__ void prep_kernel(const float* __restrict__ labels,
                            int* __restrict__ idx) {
    int n = blockIdx.x * 256 + threadIdx.x;
    if (n < N_SZ) {
        const float4* row = (const float4*)(labels + (size_t)n * C_SZ); // 25 float4
        int c = 0;
#pragma unroll
        for (int j = 0; j < C_SZ / 4; ++j) {
            float4 v = row[j];
            if (v.x > 0.5f) c = 4 * j + 0;
            if (v.y > 0.5f) c = 4 * j + 1;
            if (v.z > 0.5f) c = 4 * j + 2;
            if (v.w > 0.5f) c = 4 * j + 3;
        }
        idx[n] = c;
    }
}

// ---------------------------------------------------------------------------
// Transpose support [N][D4] float4 -> [D4][N_PAD] float4 (coalesced stream)
// ---------------------------------------------------------------------------
__global__ void transpose_kernel(const float4* __restrict__ sup4,
                                 float4* __restrict__ supT4) {
    int t = blockIdx.x * 256 + threadIdx.x; // t = dc * N_PAD + n
    int dc = t >> 11;                       // / N_PAD
    int n  = t & (N_PAD - 1);
    float4 v = make_float4(0.f, 0.f, 0.f, 0.f);
    if (n < N_SZ) v = sup4[(size_t)n * D4 + dc];
    supT4[t] = v;
}

// ---------------------------------------------------------------------------
// Main. Round-4 lesson: uniform inputs/w via LDS = broadcast through the
// vector LDS pipe (20 ds_read_b128/group = 4x the VALU cost). Uniform data
// belongs on the SCALAR pipe: direct global derefs with wave-uniform
// addresses -> s_load_dwordx4 (constant cache, overlaps VALU+VMEM).
// Support stream keeps the round-4 named-register VMEM pipeline (the fix
// for round-3's VGPR=16 serialization collapse).
// Writes scores to scratch S[B][N_PAD] -- no atomics, no out zeroing.
// ---------------------------------------------------------------------------
__global__ __launch_bounds__(256, 2) void score_kernel(
    const float4* __restrict__ inp4,   // [B][D4]
    const float4* __restrict__ supT4,  // [D4][N_PAD]
    const float4* __restrict__ w4,     // [D4]
    const float* __restrict__ bias_p,  // [1]
    float* __restrict__ S)             // [B][N_PAD] scores
{
    int tid = threadIdx.x;
    int n  = blockIdx.x * 256 + tid;
    int b0 = blockIdx.y * BT;

    // Wave-uniform row bases -> scalar loads inside the loop
    const float4* __restrict__ a0 = inp4 + (size_t)(b0 + 0) * D4;
    const float4* __restrict__ a1 = inp4 + (size_t)(b0 + 1) * D4;
    const float4* __restrict__ a2 = inp4 + (size_t)(b0 + 2) * D4;
    const float4* __restrict__ a3 = inp4 + (size_t)(b0 + 3) * D4;

    const float4* __restrict__ sp = supT4 + n;

    float acc[BT] = {0.f, 0.f, 0.f, 0.f};

    auto compute = [&](int dc, const float4& sv) {
        float4 wv = w4[dc];
        float4 av;
        av = a0[dc];
        acc[0] += wv.x * fabsf(av.x - sv.x);
        acc[0] += wv.y * fabsf(av.y - sv.y);
        acc[0] += wv.z * fabsf(av.z - sv.z);
        acc[0] += wv.w * fabsf(av.w - sv.w);
        av = a1[dc];
        acc[1] += wv.x * fabsf(av.x - sv.x);
        acc[1] += wv.y * fabsf(av.y - sv.y);
        acc[1] += wv.z * fabsf(av.z - sv.z);
        acc[1] += wv.w * fabsf(av.w - sv.w);
        av = a2[dc];
        acc[2] += wv.x * fabsf(av.x - sv.x);
        acc[2] += wv.y * fabsf(av.y - sv.y);
        acc[2] += wv.z * fabsf(av.z - sv.z);
        acc[2] += wv.w * fabsf(av.w - sv.w);
        av = a3[dc];
        acc[3] += wv.x * fabsf(av.x - sv.x);
        acc[3] += wv.y * fabsf(av.y - sv.y);
        acc[3] += wv.z * fabsf(av.z - sv.z);
        acc[3] += wv.w * fabsf(av.w - sv.w);
    };

    // Manual software pipeline: PF support chunks in flight in named regs.
    float4 c0 = sp[(size_t)0 * N_PAD];
    float4 c1 = sp[(size_t)1 * N_PAD];
    float4 c2 = sp[(size_t)2 * N_PAD];
    float4 c3 = sp[(size_t)3 * N_PAD];

#pragma unroll 1
    for (int dc = 0; dc < D4 - PF; dc += PF) {
        float4 t0 = sp[(size_t)(dc + 4) * N_PAD];
        float4 t1 = sp[(size_t)(dc + 5) * N_PAD];
        float4 t2 = sp[(size_t)(dc + 6) * N_PAD];
        float4 t3 = sp[(size_t)(dc + 7) * N_PAD];
        compute(dc + 0, c0);
        compute(dc + 1, c1);
        compute(dc + 2, c2);
        compute(dc + 3, c3);
        c0 = t0; c1 = t1; c2 = t2; c3 = t3;
    }
    compute(D4 - 4, c0);
    compute(D4 - 3, c1);
    compute(D4 - 2, c2);
    compute(D4 - 1, c3);

    float bias = *bias_p;
#pragma unroll
    for (int i = 0; i < BT; ++i) {
        float s = 1.0f / (1.0f + __expf(-(acc[i] + bias)));
        S[(size_t)(b0 + i) * N_PAD + n] = s; // coalesced; pad cols never read
    }
}

// ---------------------------------------------------------------------------
// Aggregate: one block per batch row. LDS bins for class sums + counts,
// then divide_no_nan. No global atomics, no pre-zeroing needed.
// ---------------------------------------------------------------------------
__global__ void agg_kernel(const float* __restrict__ S,
                           const int* __restrict__ idx,
                           float* __restrict__ out) {
    __shared__ float sums[C_SZ];
    __shared__ float cnts[C_SZ];
    int b = blockIdx.x;
    int t = threadIdx.x;
    if (t < C_SZ) { sums[t] = 0.f; cnts[t] = 0.f; }
    __syncthreads();
    for (int n = t; n < N_SZ; n += 256) {
        int c = idx[n];
        atomicAdd(&sums[c], S[(size_t)b * N_PAD + n]);
        atomicAdd(&cnts[c], 1.0f);
    }
    __syncthreads();
    if (t < C_SZ) {
        float cnt = cnts[t];
        out[(size_t)b * C_SZ + t] = (cnt != 0.f) ? sums[t] / cnt : 0.f;
    }
}

extern "C" void kernel_launch(void* const* d_in, const int* in_sizes, int n_in,
                              void* d_out, int out_size, void* d_ws, size_t ws_size,
                              hipStream_t stream) {
    const float* inputs  = (const float*)d_in[0]; // [B, D]
    const float* support = (const float*)d_in[1]; // [N, D]
    const float* labels  = (const float*)d_in[2]; // [N, C]
    const float* w       = (const float*)d_in[3]; // [D]
    const float* bias    = (const float*)d_in[4]; // [1]
    float* out = (float*)d_out;                   // [B, C]

    // Workspace: idx[2048] @0 (8KB, fully written by prep),
    // supT4 @16KB (4MB), S @16KB+4MB (2MB). No zeroing required anywhere.
    int*    idx   = (int*)d_ws;
    float4* supT4 = (float4*)((char*)d_ws + 16384);
    float*  S     = (float*)((char*)d_ws + 16384 + (size_t)D4 * N_PAD * sizeof(float4));

    prep_kernel<<<dim3((N_SZ + 255) / 256), dim3(256), 0, stream>>>(labels, idx);

    transpose_kernel<<<dim3(D4 * N_PAD / 256), dim3(256), 0, stream>>>(
        (const float4*)support, supT4);

    dim3 grid(N_PAD / 256, B_SZ / BT); // 8 x 64 = 512 blocks, 2 waves/SIMD
    score_kernel<<<grid, dim3(256), 0, stream>>>(
        (const float4*)inputs, supT4, (const float4*)w, bias, S);

    agg_kernel<<<dim3(B_SZ), dim3(256), 0, stream>>>(S, idx, out);
}